// Round 1
// baseline (510.473 us; speedup 1.0000x reference)
//
#include <hip/hip_runtime.h>

typedef _Float16 f16x8 __attribute__((ext_vector_type(8)));
typedef float    f32x4 __attribute__((ext_vector_type(4)));

#define MFMA16(a,b,c) __builtin_amdgcn_mfma_f32_16x16x32_f16((a),(b),(c),0,0,0)

constexpr int Bc  = 8;
constexpr int Sc  = 1024;
constexpr int Hc  = 512;
constexpr int NHc = 8;
constexpr int HDc = 64;

// ---------------------------------------------------------------------------
// Stage 1: QKV projection.  out[m][n] = sum_k hs[m][k] * W[n][k] + b[n]
// M = B*S = 8192, N = 512, K = 512, one blockIdx.z per {q,k,v}.
// Q,K stored head-split [BH][S][64] fp16; V stored transposed [BH][64][S] fp16.
// ---------------------------------------------------------------------------
__global__ __launch_bounds__(256) void qkv_proj(
    const float* __restrict__ hs,
    const float* __restrict__ Wq, const float* __restrict__ bq,
    const float* __restrict__ Wk, const float* __restrict__ bk,
    const float* __restrict__ Wv, const float* __restrict__ bv,
    _Float16* __restrict__ qws, _Float16* __restrict__ kws,
    _Float16* __restrict__ vws)
{
    const int z  = blockIdx.z;
    const float* W   = (z == 0) ? Wq : (z == 1) ? Wk : Wv;
    const float* bia = (z == 0) ? bq : (z == 1) ? bk : bv;

    const int m0 = blockIdx.x * 64;
    const int n0 = blockIdx.y * 64;
    const int tid  = threadIdx.x;
    const int w    = tid >> 6;
    const int lane = tid & 63;
    const int l15  = lane & 15;
    const int quad = lane >> 4;

    __shared__ __align__(16) _Float16 As[64][40];  // 64 rows x 32 k, pad->40
    __shared__ __align__(16) _Float16 Bs[64][40];

    f32x4 acc[4] = {};

    const int r = tid >> 2;        // 0..63: staging row
    const int c = (tid & 3) * 8;   // 0,8,16,24: staging col

    for (int kt = 0; kt < 16; ++kt) {
        const int k0 = kt * 32;
        const float4* ap = (const float4*)(hs + (size_t)(m0 + r) * 512 + k0 + c);
        const float4* bp = (const float4*)(W  + (size_t)(n0 + r) * 512 + k0 + c);
        float4 a0 = ap[0], a1 = ap[1];
        float4 b0 = bp[0], b1 = bp[1];
        __syncthreads();           // WAR: previous iter's frag reads done
        f16x8 av, bv8;
        av[0]=(_Float16)a0.x; av[1]=(_Float16)a0.y; av[2]=(_Float16)a0.z; av[3]=(_Float16)a0.w;
        av[4]=(_Float16)a1.x; av[5]=(_Float16)a1.y; av[6]=(_Float16)a1.z; av[7]=(_Float16)a1.w;
        bv8[0]=(_Float16)b0.x; bv8[1]=(_Float16)b0.y; bv8[2]=(_Float16)b0.z; bv8[3]=(_Float16)b0.w;
        bv8[4]=(_Float16)b1.x; bv8[5]=(_Float16)b1.y; bv8[6]=(_Float16)b1.z; bv8[7]=(_Float16)b1.w;
        *(f16x8*)&As[r][c] = av;
        *(f16x8*)&Bs[r][c] = bv8;
        __syncthreads();           // RAW: tile staged
        f16x8 af = *(const f16x8*)&As[w * 16 + l15][quad * 8];
#pragma unroll
        for (int nb = 0; nb < 4; ++nb) {
            f16x8 bf = *(const f16x8*)&Bs[nb * 16 + l15][quad * 8];
            acc[nb] = MFMA16(af, bf, acc[nb]);
        }
    }

#pragma unroll
    for (int nb = 0; nb < 4; ++nb) {
        const int n  = n0 + nb * 16 + l15;
        const float bvv = bia[n];
        const int h  = n >> 6;
        const int hd = n & 63;
#pragma unroll
        for (int rr = 0; rr < 4; ++rr) {
            const int m = m0 + w * 16 + quad * 4 + rr;    // C layout: row = quad*4+reg
            const int b = m >> 10;
            const int s = m & 1023;
            const float val = acc[nb][rr] + bvv;
            if (z == 0)
                qws[(((size_t)(b * NHc + h)) * Sc + s) * HDc + hd] = (_Float16)val;
            else if (z == 1)
                kws[(((size_t)(b * NHc + h)) * Sc + s) * HDc + hd] = (_Float16)val;
            else
                vws[(((size_t)(b * NHc + h)) * HDc + hd) * Sc + s] = (_Float16)val;
        }
    }
}

// ---------------------------------------------------------------------------
// Stage 2: flash attention with rel_2d_pos bias + additive mask.
// Block: 64 q rows (4 waves x 16), loop over 16 k-tiles of 64 keys.
// Cogview softmax == standard max-subtracted softmax (alpha = 32 is exact).
// ---------------------------------------------------------------------------
__global__ __launch_bounds__(256) void attn(
    const _Float16* __restrict__ qws, const _Float16* __restrict__ kws,
    const _Float16* __restrict__ vws, const float* __restrict__ rel,
    const float* __restrict__ mask, float* __restrict__ out)
{
    const int qt = blockIdx.x;      // q tile 0..15
    const int bh = blockIdx.y;      // 0..63
    const int b  = bh >> 3;
    const int h  = bh & 7;
    const int tid  = threadIdx.x;
    const int w    = tid >> 6;
    const int lane = tid & 63;
    const int l15  = lane & 15;
    const int quad = lane >> 4;
    const int q0w  = qt * 64 + w * 16;   // wave's first q row

    __shared__ __align__(16) _Float16 lds_p[4][16][72];  // pad 64->72: 2-way only

    const _Float16* qh = qws + (size_t)bh * Sc * HDc;
    const _Float16* kh = kws + (size_t)bh * Sc * HDc;
    const _Float16* vh = vws + (size_t)bh * HDc * Sc;
    const float* relh  = rel + (size_t)bh * Sc * Sc;
    const float* maskb = mask + (size_t)b * Sc;

    // Q fragments (A layout: m=l15, k=quad*8+j), resident for whole kernel
    f16x8 qf0 = *(const f16x8*)(qh + (size_t)(q0w + l15) * HDc + quad * 8);
    f16x8 qf1 = *(const f16x8*)(qh + (size_t)(q0w + l15) * HDc + 32 + quad * 8);

    float m_run[4], l_run[4];
    f32x4 o[4] = {};
#pragma unroll
    for (int rj = 0; rj < 4; ++rj) { m_run[rj] = -1e30f; l_run[rj] = 0.f; }

    for (int kt = 0; kt < 16; ++kt) {
        const int kbase = kt * 64;

        // ---- S = Q K^T -----------------------------------------------------
        f32x4 sc[4] = {};
#pragma unroll
        for (int nb = 0; nb < 4; ++nb) {
            const _Float16* kp = kh + (size_t)(kbase + nb * 16 + l15) * HDc + quad * 8;
            f16x8 kf0 = *(const f16x8*)kp;
            f16x8 kf1 = *(const f16x8*)(kp + 32);
            sc[nb] = MFMA16(qf0, kf0, sc[nb]);
            sc[nb] = MFMA16(qf1, kf1, sc[nb]);
        }

        // ---- scale + rel bias + mask (C layout: col=l15, row=quad*4+reg) ---
#pragma unroll
        for (int nb = 0; nb < 4; ++nb) {
            const int kcol = kbase + nb * 16 + l15;
            const float mk = maskb[kcol];
#pragma unroll
            for (int rj = 0; rj < 4; ++rj) {
                const int qrow = q0w + quad * 4 + rj;
                sc[nb][rj] = sc[nb][rj] * 0.125f + relh[(size_t)qrow * Sc + kcol] + mk;
            }
        }

        // ---- online softmax (per row; row lives on 16 lanes of one quad) ---
#pragma unroll
        for (int rj = 0; rj < 4; ++rj) {
            float mx = fmaxf(fmaxf(sc[0][rj], sc[1][rj]), fmaxf(sc[2][rj], sc[3][rj]));
#pragma unroll
            for (int off = 1; off < 16; off <<= 1) mx = fmaxf(mx, __shfl_xor(mx, off));
            const float mnew  = fmaxf(m_run[rj], mx);
            const float alpha = __expf(m_run[rj] - mnew);
            float rs = 0.f;
#pragma unroll
            for (int nb = 0; nb < 4; ++nb) {
                const float p = __expf(sc[nb][rj] - mnew);
                sc[nb][rj] = p;
                rs += p;
            }
#pragma unroll
            for (int off = 1; off < 16; off <<= 1) rs += __shfl_xor(rs, off);
            m_run[rj] = mnew;
            l_run[rj] = l_run[rj] * alpha + rs;
            o[0][rj] *= alpha; o[1][rj] *= alpha; o[2][rj] *= alpha; o[3][rj] *= alpha;
        }

        // ---- P: C layout -> A layout via LDS -------------------------------
        __syncthreads();   // WAR vs previous iteration's reads
#pragma unroll
        for (int nb = 0; nb < 4; ++nb)
#pragma unroll
            for (int rj = 0; rj < 4; ++rj)
                lds_p[w][quad * 4 + rj][nb * 16 + l15] = (_Float16)sc[nb][rj];
        __syncthreads();   // RAW
        f16x8 ap0 = *(const f16x8*)&lds_p[w][l15][quad * 8];
        f16x8 ap1 = *(const f16x8*)&lds_p[w][l15][32 + quad * 8];

        // ---- O += P V  (B operand from V^T: n=hd=l15, k=s_k=quad*8+j) ------
#pragma unroll
        for (int nb = 0; nb < 4; ++nb) {
            const _Float16* vp = vh + (size_t)(nb * 16 + l15) * Sc + kbase + quad * 8;
            f16x8 v0 = *(const f16x8*)vp;
            f16x8 v1 = *(const f16x8*)(vp + 32);
            o[nb] = MFMA16(ap0, v0, o[nb]);
            o[nb] = MFMA16(ap1, v1, o[nb]);
        }
    }

    // ---- epilogue: out[b, s, h*64+hd] = o / l -----------------------------
#pragma unroll
    for (int nb = 0; nb < 4; ++nb) {
#pragma unroll
        for (int rj = 0; rj < 4; ++rj) {
            const int qrow = q0w + quad * 4 + rj;
            out[((size_t)(b * Sc + qrow)) * Hc + h * HDc + nb * 16 + l15] =
                o[nb][rj] / l_run[rj];
        }
    }
}

extern "C" void kernel_launch(void* const* d_in, const int* in_sizes, int n_in,
                              void* d_out, int out_size, void* d_ws, size_t ws_size,
                              hipStream_t stream) {
    const float* hs   = (const float*)d_in[0];
    const float* mask = (const float*)d_in[1];
    const float* rel  = (const float*)d_in[2];
    const float* Wq   = (const float*)d_in[3];
    const float* bq   = (const float*)d_in[4];
    const float* Wk   = (const float*)d_in[5];
    const float* bk   = (const float*)d_in[6];
    const float* Wv   = (const float*)d_in[7];
    const float* bv   = (const float*)d_in[8];
    float* out = (float*)d_out;

    const size_t elems = (size_t)Bc * Sc * Hc;   // 4,194,304
    _Float16* qws = (_Float16*)d_ws;
    _Float16* kws = qws + elems;
    _Float16* vws = kws + elems;                 // total 24 MB of ws

    qkv_proj<<<dim3(128, 8, 3), 256, 0, stream>>>(hs, Wq, bq, Wk, bk, Wv, bv,
                                                  qws, kws, vws);
    attn<<<dim3(16, 64), 256, 0, stream>>>(qws, kws, vws, rel, mask, out);
}